// Round 5
// baseline (33500.613 us; speedup 1.0000x reference)
//
#include <hip/hip_runtime.h>
#include <hip/hip_bf16.h>

#define BTOT 16384
#define N_OUT (16384 * 216)

__device__ __forceinline__ float sig_(float x) {
    return __fdividef(1.0f, 1.0f + __expf(-x));
}
__device__ __forceinline__ float tanh_(float x) {
    float ax = fabsf(x);
    float e  = __expf(-2.0f * ax);
    float r  = __fdividef(1.0f - e, 1.0f + e);
    return x < 0.0f ? -r : r;
}

// ---------------------------------------------------------------------------
// Kernel 1: backward (5 -> 100) LSTM. grid = 256, block = 256 (4 grp x 64 rows).
// LDS = 35,456 B. Output HB bf16 [t][u][b]. Sentinel 1000.0f -> out[N-1].
// ---------------------------------------------------------------------------
__global__ __launch_bounds__(256) void k_bwd(
    const float* __restrict__ x,
    const float* __restrict__ h0b, const float* __restrict__ c0b,
    const float* __restrict__ Wih, const float* __restrict__ Whh,
    const float* __restrict__ bih, const float* __restrict__ bhh,
    __hip_bfloat16* __restrict__ HB, float* __restrict__ dbg)
{
    __shared__ float h_s[64][101];
    __shared__ float wih_s[2000];    // 400 x 5
    __shared__ float bias_s[400];

    const int tid  = threadIdx.x;
    const int r    = tid & 63;
    const int ug   = __builtin_amdgcn_readfirstlane(tid >> 6);  // 0..3
    const int u0   = ug * 25;
    const int rb   = blockIdx.x * 64;
    const int brow = rb + r;

    for (int i = tid; i < 2000; i += 256) wih_s[i] = Wih[i];
    for (int i = tid; i < 400;  i += 256) bias_s[i] = bih[i] + bhh[i];
    for (int i = tid; i < 6400; i += 256) h_s[i / 100][i % 100] = h0b[(size_t)rb * 100 + i];

    float c[25];
    #pragma unroll
    for (int k = 0; k < 25; ++k) c[k] = c0b[(size_t)brow * 100 + u0 + k];
    __syncthreads();

    for (int t = 0; t < 20; ++t) {
        const int tt = 19 - t;
        float xv[5];
        const float* xp = x + (size_t)tt * (BTOT * 5) + (size_t)brow * 5;
        #pragma unroll
        for (int i = 0; i < 5; ++i) xv[i] = xp[i];

        float hnew[25];
        #pragma unroll 1
        for (int uc = 0; uc < 5; ++uc) {
            const int ub = u0 + uc * 5;
            float acc[5][4];
            #pragma unroll
            for (int j = 0; j < 5; ++j)
                #pragma unroll
                for (int g = 0; g < 4; ++g) {
                    const int row = g * 100 + ub + j;
                    float a = bias_s[row];
                    #pragma unroll
                    for (int i = 0; i < 5; ++i) a = fmaf(xv[i], wih_s[row * 5 + i], a);
                    acc[j][g] = a;
                }
            #pragma unroll 1
            for (int i4 = 0; i4 < 25; ++i4) {          // recurrent, K = 100
                const float hv0 = h_s[r][i4 * 4 + 0];
                const float hv1 = h_s[r][i4 * 4 + 1];
                const float hv2 = h_s[r][i4 * 4 + 2];
                const float hv3 = h_s[r][i4 * 4 + 3];
                #pragma unroll
                for (int j = 0; j < 5; ++j)
                    #pragma unroll
                    for (int g = 0; g < 4; ++g) {
                        const float* wr = Whh + (size_t)(g * 100 + ub + j) * 100 + i4 * 4;
                        float a = acc[j][g];
                        a = fmaf(hv0, wr[0], a);
                        a = fmaf(hv1, wr[1], a);
                        a = fmaf(hv2, wr[2], a);
                        a = fmaf(hv3, wr[3], a);
                        acc[j][g] = a;
                    }
            }
            #pragma unroll
            for (int j = 0; j < 5; ++j) {              // gate order i,f,g,o
                const float ig = sig_(acc[j][0]);
                const float fg = sig_(acc[j][1]);
                const float gg = tanh_(acc[j][2]);
                const float og = sig_(acc[j][3]);
                const float cn = fmaf(fg, c[uc * 5 + j], ig * gg);
                c[uc * 5 + j] = cn;
                hnew[uc * 5 + j] = og * tanh_(cn);
            }
        }
        __syncthreads();
        #pragma unroll
        for (int k = 0; k < 25; ++k) {
            h_s[r][u0 + k] = hnew[k];
            HB[((size_t)tt * 100 + u0 + k) * BTOT + brow] = __float2bfloat16(hnew[k]);
        }
        __syncthreads();
    }
    if (blockIdx.x == 0 && tid == 0) dbg[N_OUT - 1] = 1000.0f;   // "k_bwd ran"
}

// ---------------------------------------------------------------------------
// Kernel 2: fused forward (5->100) + middle (200->200) LSTM.
// grid = 256, block = 256 (4 grp x 64 rows): fwd 25 units/thread, mid 50
// units/thread (accM[50][4] in regs). Two LDS buffers [64][101] carry
// {hf, hb[t], hm-lo, hm-hi} slices between barrier phases.
// Static LDS = 56,512 B. Sentinel 300.0f -> out[N-2].
// ---------------------------------------------------------------------------
__global__ __launch_bounds__(256, 1) void k_fwdmid(
    const float* __restrict__ x,
    const float* __restrict__ h0f, const float* __restrict__ c0f,
    const float* __restrict__ WihF, const float* __restrict__ WhhF,
    const float* __restrict__ bihF, const float* __restrict__ bhhF,
    const float* __restrict__ h0m, const float* __restrict__ c0m,
    const float* __restrict__ WihM, const float* __restrict__ WhhM,
    const float* __restrict__ bihM, const float* __restrict__ bhhM,
    const __hip_bfloat16* __restrict__ HB,
    float* __restrict__ HM, float* __restrict__ dbg)
{
    __shared__ float bufA[64][101];   // 25,856 B
    __shared__ float bufB[64][101];   // 25,856 B
    __shared__ float biasF_s[400];    //  1,600 B
    __shared__ float biasM_s[800];    //  3,200 B

    const int tid  = threadIdx.x;
    const int r    = tid & 63;
    const int ug   = __builtin_amdgcn_readfirstlane(tid >> 6);  // 0..3
    const int u0f  = ug * 25;
    const int u0m  = ug * 50;
    const int rb   = blockIdx.x * 64;
    const int brow = rb + r;

    for (int i = tid; i < 400; i += 256) biasF_s[i] = bihF[i] + bhhF[i];
    for (int i = tid; i < 800; i += 256) biasM_s[i] = bihM[i] + bhhM[i];

    float hf[25], cf[25];
    #pragma unroll
    for (int k = 0; k < 25; ++k) {
        hf[k] = h0f[(size_t)brow * 100 + u0f + k];
        cf[k] = c0f[(size_t)brow * 100 + u0f + k];
    }
    float hm[50], cm[50];
    #pragma unroll
    for (int k = 0; k < 50; ++k) {
        hm[k] = h0m[(size_t)brow * 200 + u0m + k];
        cm[k] = c0m[(size_t)brow * 200 + u0m + k];
    }
    __syncthreads();

    for (int t = 0; t < 20; ++t) {
        // ---- S1: publish hf[t-1] -> bufA; stage hb[t] -> bufB ----
        #pragma unroll
        for (int k = 0; k < 25; ++k) bufA[r][u0f + k] = hf[k];
        const __hip_bfloat16* HBt = HB + (size_t)t * 100 * BTOT + rb;
        for (int i = tid; i < 6400; i += 256) {
            const int rr = i & 63;
            const int u  = i >> 6;
            bufB[rr][u] = __bfloat162float(HBt[(size_t)u * BTOT + rr]);
        }
        __syncthreads();

        // ---- S2: forward LSTM step (all 4 groups, 25 units), reads bufA ----
        {
            float xv[5];
            const float* xp = x + (size_t)t * (BTOT * 5) + (size_t)brow * 5;
            #pragma unroll
            for (int i = 0; i < 5; ++i) xv[i] = xp[i];

            #pragma unroll 1
            for (int uc = 0; uc < 5; ++uc) {
                const int ub = u0f + uc * 5;
                float acc[5][4];
                #pragma unroll
                for (int j = 0; j < 5; ++j)
                    #pragma unroll
                    for (int g = 0; g < 4; ++g) {
                        const int row = g * 100 + ub + j;
                        float a = biasF_s[row];
                        const float* wr = WihF + (size_t)row * 5;
                        #pragma unroll
                        for (int i = 0; i < 5; ++i) a = fmaf(xv[i], wr[i], a);
                        acc[j][g] = a;
                    }
                #pragma unroll 1
                for (int i4 = 0; i4 < 25; ++i4) {
                    const float hv0 = bufA[r][i4 * 4 + 0];
                    const float hv1 = bufA[r][i4 * 4 + 1];
                    const float hv2 = bufA[r][i4 * 4 + 2];
                    const float hv3 = bufA[r][i4 * 4 + 3];
                    #pragma unroll
                    for (int j = 0; j < 5; ++j)
                        #pragma unroll
                        for (int g = 0; g < 4; ++g) {
                            const float* wr = WhhF + (size_t)(g * 100 + ub + j) * 100 + i4 * 4;
                            float a = acc[j][g];
                            a = fmaf(hv0, wr[0], a); a = fmaf(hv1, wr[1], a);
                            a = fmaf(hv2, wr[2], a); a = fmaf(hv3, wr[3], a);
                            acc[j][g] = a;
                        }
                }
                #pragma unroll
                for (int j = 0; j < 5; ++j) {
                    const float ig = sig_(acc[j][0]);
                    const float fg = sig_(acc[j][1]);
                    const float gg = tanh_(acc[j][2]);
                    const float og = sig_(acc[j][3]);
                    const float cn = fmaf(fg, cf[uc * 5 + j], ig * gg);
                    cf[uc * 5 + j] = cn;
                    hf[uc * 5 + j] = og * tanh_(cn);   // recurrent dot reads bufA, safe
                }
            }
        }
        __syncthreads();

        // ---- S3: publish hf[t] -> bufA ----
        #pragma unroll
        for (int k = 0; k < 25; ++k) bufA[r][u0f + k] = hf[k];
        __syncthreads();

        // ---- S4: accM = biasM + WihM[:,0:100]*hf + WihM[:,100:200]*hb ----
        float accM[50][4];
        #pragma unroll
        for (int ju = 0; ju < 50; ++ju)
            #pragma unroll
            for (int g = 0; g < 4; ++g)
                accM[ju][g] = biasM_s[g * 200 + u0m + ju];

        #pragma unroll 1
        for (int i4 = 0; i4 < 25; ++i4) {              // hf part
            const float a0 = bufA[r][i4 * 4 + 0];
            const float a1 = bufA[r][i4 * 4 + 1];
            const float a2 = bufA[r][i4 * 4 + 2];
            const float a3 = bufA[r][i4 * 4 + 3];
            #pragma unroll
            for (int ju = 0; ju < 50; ++ju)
                #pragma unroll
                for (int g = 0; g < 4; ++g) {
                    const float* wr = WihM + (size_t)(g * 200 + u0m + ju) * 200 + i4 * 4;
                    float a = accM[ju][g];
                    a = fmaf(a0, wr[0], a); a = fmaf(a1, wr[1], a);
                    a = fmaf(a2, wr[2], a); a = fmaf(a3, wr[3], a);
                    accM[ju][g] = a;
                }
        }
        #pragma unroll 1
        for (int i4 = 0; i4 < 25; ++i4) {              // hb part
            const float b0 = bufB[r][i4 * 4 + 0];
            const float b1 = bufB[r][i4 * 4 + 1];
            const float b2 = bufB[r][i4 * 4 + 2];
            const float b3 = bufB[r][i4 * 4 + 3];
            #pragma unroll
            for (int ju = 0; ju < 50; ++ju)
                #pragma unroll
                for (int g = 0; g < 4; ++g) {
                    const float* wr = WihM + (size_t)(g * 200 + u0m + ju) * 200 + 100 + i4 * 4;
                    float a = accM[ju][g];
                    a = fmaf(b0, wr[0], a); a = fmaf(b1, wr[1], a);
                    a = fmaf(b2, wr[2], a); a = fmaf(b3, wr[3], a);
                    accM[ju][g] = a;
                }
        }
        __syncthreads();

        // ---- S5: publish hm[t-1]: units 0..99 -> bufA, 100..199 -> bufB ----
        if (ug < 2) {
            #pragma unroll
            for (int k = 0; k < 50; ++k) bufA[r][ug * 50 + k] = hm[k];
        } else {
            #pragma unroll
            for (int k = 0; k < 50; ++k) bufB[r][(ug - 2) * 50 + k] = hm[k];
        }
        __syncthreads();

        // ---- S6: accM += WhhM[:,0:100]*hm_lo + WhhM[:,100:200]*hm_hi; gates ----
        #pragma unroll 1
        for (int i4 = 0; i4 < 25; ++i4) {
            const float a0 = bufA[r][i4 * 4 + 0];
            const float a1 = bufA[r][i4 * 4 + 1];
            const float a2 = bufA[r][i4 * 4 + 2];
            const float a3 = bufA[r][i4 * 4 + 3];
            #pragma unroll
            for (int ju = 0; ju < 50; ++ju)
                #pragma unroll
                for (int g = 0; g < 4; ++g) {
                    const float* wr = WhhM + (size_t)(g * 200 + u0m + ju) * 200 + i4 * 4;
                    float a = accM[ju][g];
                    a = fmaf(a0, wr[0], a); a = fmaf(a1, wr[1], a);
                    a = fmaf(a2, wr[2], a); a = fmaf(a3, wr[3], a);
                    accM[ju][g] = a;
                }
        }
        #pragma unroll 1
        for (int i4 = 0; i4 < 25; ++i4) {
            const float b0 = bufB[r][i4 * 4 + 0];
            const float b1 = bufB[r][i4 * 4 + 1];
            const float b2 = bufB[r][i4 * 4 + 2];
            const float b3 = bufB[r][i4 * 4 + 3];
            #pragma unroll
            for (int ju = 0; ju < 50; ++ju)
                #pragma unroll
                for (int g = 0; g < 4; ++g) {
                    const float* wr = WhhM + (size_t)(g * 200 + u0m + ju) * 200 + 100 + i4 * 4;
                    float a = accM[ju][g];
                    a = fmaf(b0, wr[0], a); a = fmaf(b1, wr[1], a);
                    a = fmaf(b2, wr[2], a); a = fmaf(b3, wr[3], a);
                    accM[ju][g] = a;
                }
        }
        #pragma unroll
        for (int ju = 0; ju < 50; ++ju) {
            const float ig = sig_(accM[ju][0]);
            const float fg = sig_(accM[ju][1]);
            const float gg = tanh_(accM[ju][2]);
            const float og = sig_(accM[ju][3]);
            const float cn = fmaf(fg, cm[ju], ig * gg);
            cm[ju] = cn;
            hm[ju] = og * tanh_(cn);
        }
        __syncthreads();   // protect bufA/bufB before next S1
    }

    #pragma unroll
    for (int k = 0; k < 50; ++k)
        HM[(size_t)brow * 200 + u0m + k] = hm[k];

    if (blockIdx.x == 0 && tid == 0) dbg[N_OUT - 2] = 300.0f;    // "k_fwdmid ran"
}

// ---------------------------------------------------------------------------
// Kernel 3: dense (200->27) + convT1+bn+relu + convT2+bn+relu + convT3.
// Literal transposed-conv formula. grid = 16384, block = 256. LDS = 57,740 B.
// Output FLOAT32. Block 16383 decodes sentinels; writes code only on anomaly.
// ---------------------------------------------------------------------------
__global__ __launch_bounds__(256) void k_head(
    const float* __restrict__ HM,
    const float* __restrict__ Wd, const float* __restrict__ bd,
    const float* __restrict__ w1, const float* __restrict__ b1,
    const float* __restrict__ w2, const float* __restrict__ b2,
    const float* __restrict__ w3, const float* __restrict__ b3,
    const float* __restrict__ g1, const float* __restrict__ be1,
    const float* __restrict__ m1, const float* __restrict__ v1,
    const float* __restrict__ g2, const float* __restrict__ be2,
    const float* __restrict__ m2, const float* __restrict__ v2,
    float* out)
{
    __shared__ float hm_s[200];
    __shared__ float y27[27];
    __shared__ float t1[128][54];
    __shared__ float t2[64][108];
    __shared__ float sc1[128], sh1[128], sc2[64], sh2[64];

    const int tid = threadIdx.x;
    const int b   = blockIdx.x;

    // read sentinels BEFORE this block writes anything (block 16383 owns them)
    float diag1 = 1000.0f, diag2 = 300.0f;
    if (b == 16383 && tid == 0) {
        diag1 = out[N_OUT - 1];
        diag2 = out[N_OUT - 2];
    }

    if (tid < 200) hm_s[tid] = HM[(size_t)b * 200 + tid];
    if (tid < 128) {
        const float s = g1[tid] * __frsqrt_rn(v1[tid] + 1e-5f);
        sc1[tid] = s; sh1[tid] = be1[tid] - m1[tid] * s;
    } else if (tid < 192) {
        const int cc = tid - 128;
        const float s = g2[cc] * __frsqrt_rn(v2[cc] + 1e-5f);
        sc2[cc] = s; sh2[cc] = be2[cc] - m2[cc] * s;
    }
    __syncthreads();

    float hmsum = 1.0f;
    if (b == 16383 && tid == 0) {
        hmsum = 0.0f;
        for (int i = 0; i < 200; ++i) hmsum += fabsf(hm_s[i]);
    }

    if (tid < 27) {                                   // dense 200 -> 27
        float a = bd[tid];
        const float* wr = Wd + tid * 200;
        for (int i = 0; i < 200; ++i) a = fmaf(hm_s[i], wr[i], a);
        y27[tid] = a;
    }
    __syncthreads();

    // conv1 (1 -> 128, 27 -> 54) + bn1 + relu
    for (int idx = tid; idx < 128 * 54; idx += 256) {
        const int co = idx / 54;
        const int l  = idx - co * 54;
        float a = b1[co];
        #pragma unroll
        for (int k = 0; k < 4; ++k) {
            const int i2 = l + 1 - k;
            if (i2 & 1) continue;
            const int i = i2 >> 1;
            if (i < 0 || i >= 27) continue;
            a = fmaf(y27[i], w1[co * 4 + k], a);
        }
        a = fmaf(a, sc1[co], sh1[co]);
        t1[co][l] = fmaxf(a, 0.0f);
    }
    __syncthreads();

    // conv2 (128 -> 64, 54 -> 108) + bn2 + relu. thread = 4 co x 7 l block.
    {
        const int co0 = (tid >> 4) * 4;
        const int l0  = (tid & 15) * 7;
        float acc[4][7];
        #pragma unroll
        for (int cJ = 0; cJ < 4; ++cJ) {
            const float bb = b2[co0 + cJ];
            #pragma unroll
            for (int jl = 0; jl < 7; ++jl) acc[cJ][jl] = bb;
        }
        #pragma unroll 1
        for (int ci = 0; ci < 128; ++ci) {
            float wv[4][4];
            #pragma unroll
            for (int cJ = 0; cJ < 4; ++cJ)
                #pragma unroll
                for (int k = 0; k < 4; ++k)
                    wv[cJ][k] = w2[((size_t)(ci * 64 + co0 + cJ)) * 4 + k];
            #pragma unroll
            for (int jl = 0; jl < 7; ++jl) {
                const int l = l0 + jl;
                #pragma unroll
                for (int k = 0; k < 4; ++k) {
                    const int i2 = l + 1 - k;
                    if (i2 & 1) continue;
                    const int i = i2 >> 1;
                    if (i < 0 || i >= 54) continue;
                    const float v = t1[ci][i];
                    #pragma unroll
                    for (int cJ = 0; cJ < 4; ++cJ)
                        acc[cJ][jl] = fmaf(v, wv[cJ][k], acc[cJ][jl]);
                }
            }
        }
        #pragma unroll
        for (int cJ = 0; cJ < 4; ++cJ) {
            const int co = co0 + cJ;
            const float s2  = sc2[co];
            const float h2v = sh2[co];
            #pragma unroll
            for (int jl = 0; jl < 7; ++jl) {
                const int l = l0 + jl;
                if (l < 108) t2[co][l] = fmaxf(fmaf(acc[cJ][jl], s2, h2v), 0.0f);
            }
        }
    }
    __syncthreads();

    // conv3 (64 -> 1, 108 -> 216), FLOAT32 output
    if (tid < 216) {
        const int l = tid;
        float a = b3[0];
        #pragma unroll 1
        for (int ci = 0; ci < 64; ++ci) {
            #pragma unroll
            for (int k = 0; k < 4; ++k) {
                const int i2 = l + 1 - k;
                if (i2 & 1) continue;
                const int i = i2 >> 1;
                if (i < 0 || i >= 108) continue;
                a = fmaf(t2[ci][i], w3[ci * 4 + k], a);
            }
        }
        out[(size_t)b * 216 + l] = a;
    }

    // diagnostic code (only on anomaly; healthy run leaves output clean)
    if (b == 16383 && tid == 0) {
        float code = 0.0f;
        if (diag1 != 1000.0f) code += 1000.0f;   // k_bwd never ran
        if (diag2 != 300.0f)  code += 300.0f;    // k_fwdmid never ran
        if (hmsum < 1e-6f)    code += 100.0f;    // HM reads as zero
        if (code != 0.0f) out[(size_t)b * 216] = code;
    }
}

// ---------------------------------------------------------------------------
extern "C" void kernel_launch(void* const* d_in, const int* in_sizes, int n_in,
                              void* d_out, int out_size, void* d_ws, size_t ws_size,
                              hipStream_t stream) {
    const float* x     = (const float*)d_in[0];
    const float* h0f   = (const float*)d_in[1];
    const float* c0f   = (const float*)d_in[2];
    const float* h0b   = (const float*)d_in[3];
    const float* c0b   = (const float*)d_in[4];
    const float* h0m   = (const float*)d_in[5];
    const float* c0m   = (const float*)d_in[6];
    const float* Wih_f = (const float*)d_in[7];
    const float* Whh_f = (const float*)d_in[8];
    const float* bih_f = (const float*)d_in[9];
    const float* bhh_f = (const float*)d_in[10];
    const float* Wih_b = (const float*)d_in[11];
    const float* Whh_b = (const float*)d_in[12];
    const float* bih_b = (const float*)d_in[13];
    const float* bhh_b = (const float*)d_in[14];
    const float* Wih_m = (const float*)d_in[15];
    const float* Whh_m = (const float*)d_in[16];
    const float* bih_m = (const float*)d_in[17];
    const float* bhh_m = (const float*)d_in[18];
    const float* Wd    = (const float*)d_in[19];
    const float* bd    = (const float*)d_in[20];
    const float* w1    = (const float*)d_in[21];
    const float* b1    = (const float*)d_in[22];
    const float* w2    = (const float*)d_in[23];
    const float* b2    = (const float*)d_in[24];
    const float* w3    = (const float*)d_in[25];
    const float* b3    = (const float*)d_in[26];
    const float* g1    = (const float*)d_in[27];
    const float* be1   = (const float*)d_in[28];
    const float* m1    = (const float*)d_in[29];
    const float* v1    = (const float*)d_in[30];
    const float* g2    = (const float*)d_in[31];
    const float* be2   = (const float*)d_in[32];
    const float* m2    = (const float*)d_in[33];
    const float* v2    = (const float*)d_in[34];

    // ws: HB bf16 [20][100][16384] = 65,536,000 B; HM f32 [16384][200] = 13,107,200 B
    __hip_bfloat16* HB = (__hip_bfloat16*)d_ws;
    float* HM  = (float*)((char*)d_ws + 65536000);
    float* out = (float*)d_out;

    k_bwd<<<256, 256, 0, stream>>>(
        x, h0b, c0b, Wih_b, Whh_b, bih_b, bhh_b, HB, out);

    k_fwdmid<<<256, 256, 0, stream>>>(
        x, h0f, c0f, Wih_f, Whh_f, bih_f, bhh_f,
        h0m, c0m, Wih_m, Whh_m, bih_m, bhh_m, HB, HM, out);

    k_head<<<16384, 256, 0, stream>>>(
        HM, Wd, bd, w1, b1, w2, b2, w3, b3,
        g1, be1, m1, v1, g2, be2, m2, v2, out);
}

// Round 6
// 20111.632 us; speedup vs baseline: 1.6657x; 1.6657x over previous
//
#include <hip/hip_runtime.h>
#include <hip/hip_bf16.h>

#define BTOT 16384

__device__ __forceinline__ float sig_(float x) {
    return __fdividef(1.0f, 1.0f + __expf(-x));
}
__device__ __forceinline__ float tanh_(float x) {
    float ax = fabsf(x);
    float e  = __expf(-2.0f * ax);
    float r  = __fdividef(1.0f - e, 1.0f + e);
    return x < 0.0f ? -r : r;
}

// ---------------------------------------------------------------------------
// Kernel 1: the two (5 -> 100) LSTMs. grid = (256, ny), block = 256.
// dir = blockIdx.y + dir0: 0 = forward (t ascending), 1 = backward (reversed).
// 4 groups x 64 rows; h in LDS (stride 101), c in regs. LDS = 35,456 B.
// Output H{F,B} bf16 [t][u][b].
// ---------------------------------------------------------------------------
__global__ __launch_bounds__(256, 4) void k_lstm100(
    const float* __restrict__ x,
    const float* __restrict__ h0f, const float* __restrict__ c0f,
    const float* __restrict__ h0b, const float* __restrict__ c0b,
    const float* __restrict__ WihF, const float* __restrict__ WhhF,
    const float* __restrict__ bihF, const float* __restrict__ bhhF,
    const float* __restrict__ WihB, const float* __restrict__ WhhB,
    const float* __restrict__ bihB, const float* __restrict__ bhhB,
    __hip_bfloat16* __restrict__ HF, __hip_bfloat16* __restrict__ HB,
    int dir0)
{
    const int dir = blockIdx.y + dir0;
    const float* h0  = dir ? h0b : h0f;
    const float* c0  = dir ? c0b : c0f;
    const float* Wih = dir ? WihB : WihF;
    const float* Whh = dir ? WhhB : WhhF;
    const float* bih = dir ? bihB : bihF;
    const float* bhh = dir ? bhhB : bhhF;
    __hip_bfloat16* Hout = dir ? HB : HF;

    __shared__ float h_s[64][101];
    __shared__ float wih_s[2000];    // 400 x 5
    __shared__ float bias_s[400];

    const int tid  = threadIdx.x;
    const int r    = tid & 63;
    const int ug   = __builtin_amdgcn_readfirstlane(tid >> 6);  // 0..3
    const int u0   = ug * 25;
    const int rb   = blockIdx.x * 64;
    const int brow = rb + r;

    for (int i = tid; i < 2000; i += 256) wih_s[i] = Wih[i];
    for (int i = tid; i < 400;  i += 256) bias_s[i] = bih[i] + bhh[i];
    for (int i = tid; i < 6400; i += 256) h_s[i / 100][i % 100] = h0[(size_t)rb * 100 + i];

    float c[25];
    #pragma unroll
    for (int k = 0; k < 25; ++k) c[k] = c0[(size_t)brow * 100 + u0 + k];
    __syncthreads();

    for (int t = 0; t < 20; ++t) {
        const int tt = dir ? (19 - t) : t;
        float xv[5];
        const float* xp = x + (size_t)tt * (BTOT * 5) + (size_t)brow * 5;
        #pragma unroll
        for (int i = 0; i < 5; ++i) xv[i] = xp[i];

        float hnew[25];
        #pragma unroll 1
        for (int uc = 0; uc < 5; ++uc) {
            const int ub = u0 + uc * 5;
            float acc[5][4];
            #pragma unroll
            for (int j = 0; j < 5; ++j)
                #pragma unroll
                for (int g = 0; g < 4; ++g) {
                    const int row = g * 100 + ub + j;
                    float a = bias_s[row];
                    #pragma unroll
                    for (int i = 0; i < 5; ++i) a = fmaf(xv[i], wih_s[row * 5 + i], a);
                    acc[j][g] = a;
                }
            #pragma unroll 1
            for (int i4 = 0; i4 < 25; ++i4) {          // recurrent, K = 100
                const float hv0 = h_s[r][i4 * 4 + 0];
                const float hv1 = h_s[r][i4 * 4 + 1];
                const float hv2 = h_s[r][i4 * 4 + 2];
                const float hv3 = h_s[r][i4 * 4 + 3];
                #pragma unroll
                for (int j = 0; j < 5; ++j)
                    #pragma unroll
                    for (int g = 0; g < 4; ++g) {
                        const float* wr = Whh + (size_t)(g * 100 + ub + j) * 100 + i4 * 4;
                        float a = acc[j][g];
                        a = fmaf(hv0, wr[0], a);
                        a = fmaf(hv1, wr[1], a);
                        a = fmaf(hv2, wr[2], a);
                        a = fmaf(hv3, wr[3], a);
                        acc[j][g] = a;
                    }
            }
            #pragma unroll
            for (int j = 0; j < 5; ++j) {              // gate order i,f,g,o
                const float ig = sig_(acc[j][0]);
                const float fg = sig_(acc[j][1]);
                const float gg = tanh_(acc[j][2]);
                const float og = sig_(acc[j][3]);
                const float cn = fmaf(fg, c[uc * 5 + j], ig * gg);
                c[uc * 5 + j] = cn;
                hnew[uc * 5 + j] = og * tanh_(cn);
            }
        }
        __syncthreads();
        #pragma unroll
        for (int k = 0; k < 25; ++k) {
            h_s[r][u0 + k] = hnew[k];
            Hout[((size_t)tt * 100 + u0 + k) * BTOT + brow] = __float2bfloat16(hnew[k]);
        }
        __syncthreads();
    }
}

// ---------------------------------------------------------------------------
// Kernel 2 (plan A): middle (200 -> 200) LSTM. grid = 256, block = 512
// (8 wave-groups x 64 rows, 25 units/thread: acc[25][4] = 100 regs, no spill).
// Per t: stage hf/hb tiles (bf16) -> bufA/bufB; input-part accumulate;
// publish hm lo/hi -> bufA/bufB; recurrent accumulate; gates.
// LDS = 54,912 B. Final h -> HM f32 [b][u].
// ---------------------------------------------------------------------------
__global__ __launch_bounds__(512, 2) void k_mid(
    const float* __restrict__ h0m, const float* __restrict__ c0m,
    const float* __restrict__ Wih, const float* __restrict__ Whh,
    const float* __restrict__ bih, const float* __restrict__ bhh,
    const __hip_bfloat16* __restrict__ HF, const __hip_bfloat16* __restrict__ HB,
    float* __restrict__ HM)
{
    __shared__ float bufA[64][101];   // 25,856 B
    __shared__ float bufB[64][101];   // 25,856 B
    __shared__ float bias_s[800];     //  3,200 B

    const int tid  = threadIdx.x;
    const int r    = tid & 63;
    const int ug   = __builtin_amdgcn_readfirstlane(tid >> 6);  // 0..7
    const int u0   = ug * 25;
    const int rb   = blockIdx.x * 64;
    const int brow = rb + r;

    for (int i = tid; i < 800; i += 512) bias_s[i] = bih[i] + bhh[i];

    float hm[25], cm[25];
    #pragma unroll
    for (int k = 0; k < 25; ++k) {
        hm[k] = h0m[(size_t)brow * 200 + u0 + k];
        cm[k] = c0m[(size_t)brow * 200 + u0 + k];
    }
    __syncthreads();

    for (int t = 0; t < 20; ++t) {
        // ---- S1: stage hf[t] -> bufA, hb[t] -> bufB (bf16 -> f32) ----
        const __hip_bfloat16* HFt = HF + (size_t)t * 100 * BTOT + rb;
        const __hip_bfloat16* HBt = HB + (size_t)t * 100 * BTOT + rb;
        for (int i = tid; i < 6400; i += 512) {
            const int rr = i & 63;
            const int u  = i >> 6;
            bufA[rr][u] = __bfloat162float(HFt[(size_t)u * BTOT + rr]);
            bufB[rr][u] = __bfloat162float(HBt[(size_t)u * BTOT + rr]);
        }
        __syncthreads();

        // ---- S2: acc = bias + Wih[:,0:100]*hf + Wih[:,100:200]*hb ----
        float acc[25][4];
        #pragma unroll
        for (int ju = 0; ju < 25; ++ju)
            #pragma unroll
            for (int g = 0; g < 4; ++g)
                acc[ju][g] = bias_s[g * 200 + u0 + ju];

        #pragma unroll 1
        for (int i4 = 0; i4 < 25; ++i4) {              // hf part
            const float a0 = bufA[r][i4 * 4 + 0];
            const float a1 = bufA[r][i4 * 4 + 1];
            const float a2 = bufA[r][i4 * 4 + 2];
            const float a3 = bufA[r][i4 * 4 + 3];
            #pragma unroll
            for (int ju = 0; ju < 25; ++ju)
                #pragma unroll
                for (int g = 0; g < 4; ++g) {
                    const float* wr = Wih + (size_t)(g * 200 + u0 + ju) * 200 + i4 * 4;
                    float a = acc[ju][g];
                    a = fmaf(a0, wr[0], a); a = fmaf(a1, wr[1], a);
                    a = fmaf(a2, wr[2], a); a = fmaf(a3, wr[3], a);
                    acc[ju][g] = a;
                }
        }
        #pragma unroll 1
        for (int i4 = 0; i4 < 25; ++i4) {              // hb part
            const float b0 = bufB[r][i4 * 4 + 0];
            const float b1 = bufB[r][i4 * 4 + 1];
            const float b2 = bufB[r][i4 * 4 + 2];
            const float b3 = bufB[r][i4 * 4 + 3];
            #pragma unroll
            for (int ju = 0; ju < 25; ++ju)
                #pragma unroll
                for (int g = 0; g < 4; ++g) {
                    const float* wr = Wih + (size_t)(g * 200 + u0 + ju) * 200 + 100 + i4 * 4;
                    float a = acc[ju][g];
                    a = fmaf(b0, wr[0], a); a = fmaf(b1, wr[1], a);
                    a = fmaf(b2, wr[2], a); a = fmaf(b3, wr[3], a);
                    acc[ju][g] = a;
                }
        }
        __syncthreads();           // all reads of hf/hb tiles done

        // ---- S3: publish hm[t-1]: units 0..99 -> bufA, 100..199 -> bufB ----
        if (ug < 4) {
            #pragma unroll
            for (int k = 0; k < 25; ++k) bufA[r][ug * 25 + k] = hm[k];
        } else {
            #pragma unroll
            for (int k = 0; k < 25; ++k) bufB[r][(ug - 4) * 25 + k] = hm[k];
        }
        __syncthreads();

        // ---- S4: acc += Whh[:,0:100]*hm_lo + Whh[:,100:200]*hm_hi; gates ----
        #pragma unroll 1
        for (int i4 = 0; i4 < 25; ++i4) {
            const float a0 = bufA[r][i4 * 4 + 0];
            const float a1 = bufA[r][i4 * 4 + 1];
            const float a2 = bufA[r][i4 * 4 + 2];
            const float a3 = bufA[r][i4 * 4 + 3];
            #pragma unroll
            for (int ju = 0; ju < 25; ++ju)
                #pragma unroll
                for (int g = 0; g < 4; ++g) {
                    const float* wr = Whh + (size_t)(g * 200 + u0 + ju) * 200 + i4 * 4;
                    float a = acc[ju][g];
                    a = fmaf(a0, wr[0], a); a = fmaf(a1, wr[1], a);
                    a = fmaf(a2, wr[2], a); a = fmaf(a3, wr[3], a);
                    acc[ju][g] = a;
                }
        }
        #pragma unroll 1
        for (int i4 = 0; i4 < 25; ++i4) {
            const float b0 = bufB[r][i4 * 4 + 0];
            const float b1 = bufB[r][i4 * 4 + 1];
            const float b2 = bufB[r][i4 * 4 + 2];
            const float b3 = bufB[r][i4 * 4 + 3];
            #pragma unroll
            for (int ju = 0; ju < 25; ++ju)
                #pragma unroll
                for (int g = 0; g < 4; ++g) {
                    const float* wr = Whh + (size_t)(g * 200 + u0 + ju) * 200 + 100 + i4 * 4;
                    float a = acc[ju][g];
                    a = fmaf(b0, wr[0], a); a = fmaf(b1, wr[1], a);
                    a = fmaf(b2, wr[2], a); a = fmaf(b3, wr[3], a);
                    acc[ju][g] = a;
                }
        }
        #pragma unroll
        for (int ju = 0; ju < 25; ++ju) {
            const float ig = sig_(acc[ju][0]);
            const float fg = sig_(acc[ju][1]);
            const float gg = tanh_(acc[ju][2]);
            const float og = sig_(acc[ju][3]);
            const float cn = fmaf(fg, cm[ju], ig * gg);
            cm[ju] = cn;
            hm[ju] = og * tanh_(cn);
        }
        __syncthreads();           // protect bufA/bufB before next S1
    }

    #pragma unroll
    for (int k = 0; k < 25; ++k)
        HM[(size_t)brow * 200 + u0 + k] = hm[k];
}

// ---------------------------------------------------------------------------
// Kernel 2 (plan B fallback, proven in round 5): fused fwd + mid LSTM.
// Used only when ws_size cannot hold the HF buffer.
// ---------------------------------------------------------------------------
__global__ __launch_bounds__(256, 1) void k_fwdmid(
    const float* __restrict__ x,
    const float* __restrict__ h0f, const float* __restrict__ c0f,
    const float* __restrict__ WihF, const float* __restrict__ WhhF,
    const float* __restrict__ bihF, const float* __restrict__ bhhF,
    const float* __restrict__ h0m, const float* __restrict__ c0m,
    const float* __restrict__ WihM, const float* __restrict__ WhhM,
    const float* __restrict__ bihM, const float* __restrict__ bhhM,
    const __hip_bfloat16* __restrict__ HB,
    float* __restrict__ HM)
{
    __shared__ float bufA[64][101];
    __shared__ float bufB[64][101];
    __shared__ float biasF_s[400];
    __shared__ float biasM_s[800];

    const int tid  = threadIdx.x;
    const int r    = tid & 63;
    const int ug   = __builtin_amdgcn_readfirstlane(tid >> 6);  // 0..3
    const int u0f  = ug * 25;
    const int u0m  = ug * 50;
    const int rb   = blockIdx.x * 64;
    const int brow = rb + r;

    for (int i = tid; i < 400; i += 256) biasF_s[i] = bihF[i] + bhhF[i];
    for (int i = tid; i < 800; i += 256) biasM_s[i] = bihM[i] + bhhM[i];

    float hf[25], cf[25];
    #pragma unroll
    for (int k = 0; k < 25; ++k) {
        hf[k] = h0f[(size_t)brow * 100 + u0f + k];
        cf[k] = c0f[(size_t)brow * 100 + u0f + k];
    }
    float hm[50], cm[50];
    #pragma unroll
    for (int k = 0; k < 50; ++k) {
        hm[k] = h0m[(size_t)brow * 200 + u0m + k];
        cm[k] = c0m[(size_t)brow * 200 + u0m + k];
    }
    __syncthreads();

    for (int t = 0; t < 20; ++t) {
        #pragma unroll
        for (int k = 0; k < 25; ++k) bufA[r][u0f + k] = hf[k];
        const __hip_bfloat16* HBt = HB + (size_t)t * 100 * BTOT + rb;
        for (int i = tid; i < 6400; i += 256) {
            const int rr = i & 63;
            const int u  = i >> 6;
            bufB[rr][u] = __bfloat162float(HBt[(size_t)u * BTOT + rr]);
        }
        __syncthreads();

        {
            float xv[5];
            const float* xp = x + (size_t)t * (BTOT * 5) + (size_t)brow * 5;
            #pragma unroll
            for (int i = 0; i < 5; ++i) xv[i] = xp[i];

            #pragma unroll 1
            for (int uc = 0; uc < 5; ++uc) {
                const int ub = u0f + uc * 5;
                float acc[5][4];
                #pragma unroll
                for (int j = 0; j < 5; ++j)
                    #pragma unroll
                    for (int g = 0; g < 4; ++g) {
                        const int row = g * 100 + ub + j;
                        float a = biasF_s[row];
                        const float* wr = WihF + (size_t)row * 5;
                        #pragma unroll
                        for (int i = 0; i < 5; ++i) a = fmaf(xv[i], wr[i], a);
                        acc[j][g] = a;
                    }
                #pragma unroll 1
                for (int i4 = 0; i4 < 25; ++i4) {
                    const float hv0 = bufA[r][i4 * 4 + 0];
                    const float hv1 = bufA[r][i4 * 4 + 1];
                    const float hv2 = bufA[r][i4 * 4 + 2];
                    const float hv3 = bufA[r][i4 * 4 + 3];
                    #pragma unroll
                    for (int j = 0; j < 5; ++j)
                        #pragma unroll
                        for (int g = 0; g < 4; ++g) {
                            const float* wr = WhhF + (size_t)(g * 100 + ub + j) * 100 + i4 * 4;
                            float a = acc[j][g];
                            a = fmaf(hv0, wr[0], a); a = fmaf(hv1, wr[1], a);
                            a = fmaf(hv2, wr[2], a); a = fmaf(hv3, wr[3], a);
                            acc[j][g] = a;
                        }
                }
                #pragma unroll
                for (int j = 0; j < 5; ++j) {
                    const float ig = sig_(acc[j][0]);
                    const float fg = sig_(acc[j][1]);
                    const float gg = tanh_(acc[j][2]);
                    const float og = sig_(acc[j][3]);
                    const float cn = fmaf(fg, cf[uc * 5 + j], ig * gg);
                    cf[uc * 5 + j] = cn;
                    hf[uc * 5 + j] = og * tanh_(cn);
                }
            }
        }
        __syncthreads();
        #pragma unroll
        for (int k = 0; k < 25; ++k) bufA[r][u0f + k] = hf[k];
        __syncthreads();

        float accM[50][4];
        #pragma unroll
        for (int ju = 0; ju < 50; ++ju)
            #pragma unroll
            for (int g = 0; g < 4; ++g)
                accM[ju][g] = biasM_s[g * 200 + u0m + ju];

        #pragma unroll 1
        for (int i4 = 0; i4 < 25; ++i4) {
            const float a0 = bufA[r][i4 * 4 + 0];
            const float a1 = bufA[r][i4 * 4 + 1];
            const float a2 = bufA[r][i4 * 4 + 2];
            const float a3 = bufA[r][i4 * 4 + 3];
            #pragma unroll
            for (int ju = 0; ju < 50; ++ju)
                #pragma unroll
                for (int g = 0; g < 4; ++g) {
                    const float* wr = WihM + (size_t)(g * 200 + u0m + ju) * 200 + i4 * 4;
                    float a = accM[ju][g];
                    a = fmaf(a0, wr[0], a); a = fmaf(a1, wr[1], a);
                    a = fmaf(a2, wr[2], a); a = fmaf(a3, wr[3], a);
                    accM[ju][g] = a;
                }
        }
        #pragma unroll 1
        for (int i4 = 0; i4 < 25; ++i4) {
            const float b0 = bufB[r][i4 * 4 + 0];
            const float b1 = bufB[r][i4 * 4 + 1];
            const float b2 = bufB[r][i4 * 4 + 2];
            const float b3 = bufB[r][i4 * 4 + 3];
            #pragma unroll
            for (int ju = 0; ju < 50; ++ju)
                #pragma unroll
                for (int g = 0; g < 4; ++g) {
                    const float* wr = WihM + (size_t)(g * 200 + u0m + ju) * 200 + 100 + i4 * 4;
                    float a = accM[ju][g];
                    a = fmaf(b0, wr[0], a); a = fmaf(b1, wr[1], a);
                    a = fmaf(b2, wr[2], a); a = fmaf(b3, wr[3], a);
                    accM[ju][g] = a;
                }
        }
        __syncthreads();

        if (ug < 2) {
            #pragma unroll
            for (int k = 0; k < 50; ++k) bufA[r][ug * 50 + k] = hm[k];
        } else {
            #pragma unroll
            for (int k = 0; k < 50; ++k) bufB[r][(ug - 2) * 50 + k] = hm[k];
        }
        __syncthreads();

        #pragma unroll 1
        for (int i4 = 0; i4 < 25; ++i4) {
            const float a0 = bufA[r][i4 * 4 + 0];
            const float a1 = bufA[r][i4 * 4 + 1];
            const float a2 = bufA[r][i4 * 4 + 2];
            const float a3 = bufA[r][i4 * 4 + 3];
            #pragma unroll
            for (int ju = 0; ju < 50; ++ju)
                #pragma unroll
                for (int g = 0; g < 4; ++g) {
                    const float* wr = WhhM + (size_t)(g * 200 + u0m + ju) * 200 + i4 * 4;
                    float a = accM[ju][g];
                    a = fmaf(a0, wr[0], a); a = fmaf(a1, wr[1], a);
                    a = fmaf(a2, wr[2], a); a = fmaf(a3, wr[3], a);
                    accM[ju][g] = a;
                }
        }
        #pragma unroll 1
        for (int i4 = 0; i4 < 25; ++i4) {
            const float b0 = bufB[r][i4 * 4 + 0];
            const float b1 = bufB[r][i4 * 4 + 1];
            const float b2 = bufB[r][i4 * 4 + 2];
            const float b3 = bufB[r][i4 * 4 + 3];
            #pragma unroll
            for (int ju = 0; ju < 50; ++ju)
                #pragma unroll
                for (int g = 0; g < 4; ++g) {
                    const float* wr = WhhM + (size_t)(g * 200 + u0m + ju) * 200 + 100 + i4 * 4;
                    float a = accM[ju][g];
                    a = fmaf(b0, wr[0], a); a = fmaf(b1, wr[1], a);
                    a = fmaf(b2, wr[2], a); a = fmaf(b3, wr[3], a);
                    accM[ju][g] = a;
                }
        }
        #pragma unroll
        for (int ju = 0; ju < 50; ++ju) {
            const float ig = sig_(accM[ju][0]);
            const float fg = sig_(accM[ju][1]);
            const float gg = tanh_(accM[ju][2]);
            const float og = sig_(accM[ju][3]);
            const float cn = fmaf(fg, cm[ju], ig * gg);
            cm[ju] = cn;
            hm[ju] = og * tanh_(cn);
        }
        __syncthreads();
    }

    #pragma unroll
    for (int k = 0; k < 50; ++k)
        HM[(size_t)brow * 200 + u0m + k] = hm[k];
}

// ---------------------------------------------------------------------------
// Kernel 3: dense (200->27) + convT1+bn+relu + convT2+bn+relu + convT3.
// Literal transposed-conv formula. grid = 16384, block = 256. f32 output.
// ---------------------------------------------------------------------------
__global__ __launch_bounds__(256) void k_head(
    const float* __restrict__ HM,
    const float* __restrict__ Wd, const float* __restrict__ bd,
    const float* __restrict__ w1, const float* __restrict__ b1,
    const float* __restrict__ w2, const float* __restrict__ b2,
    const float* __restrict__ w3, const float* __restrict__ b3,
    const float* __restrict__ g1, const float* __restrict__ be1,
    const float* __restrict__ m1, const float* __restrict__ v1,
    const float* __restrict__ g2, const float* __restrict__ be2,
    const float* __restrict__ m2, const float* __restrict__ v2,
    float* __restrict__ out)
{
    __shared__ float hm_s[200];
    __shared__ float y27[27];
    __shared__ float t1[128][54];
    __shared__ float t2[64][108];
    __shared__ float sc1[128], sh1[128], sc2[64], sh2[64];

    const int tid = threadIdx.x;
    const int b   = blockIdx.x;

    if (tid < 200) hm_s[tid] = HM[(size_t)b * 200 + tid];
    if (tid < 128) {
        const float s = g1[tid] * __frsqrt_rn(v1[tid] + 1e-5f);
        sc1[tid] = s; sh1[tid] = be1[tid] - m1[tid] * s;
    } else if (tid < 192) {
        const int cc = tid - 128;
        const float s = g2[cc] * __frsqrt_rn(v2[cc] + 1e-5f);
        sc2[cc] = s; sh2[cc] = be2[cc] - m2[cc] * s;
    }
    __syncthreads();

    if (tid < 27) {                                   // dense 200 -> 27
        float a = bd[tid];
        const float* wr = Wd + tid * 200;
        for (int i = 0; i < 200; ++i) a = fmaf(hm_s[i], wr[i], a);
        y27[tid] = a;
    }
    __syncthreads();

    // conv1 (1 -> 128, 27 -> 54) + bn1 + relu
    for (int idx = tid; idx < 128 * 54; idx += 256) {
        const int co = idx / 54;
        const int l  = idx - co * 54;
        float a = b1[co];
        #pragma unroll
        for (int k = 0; k < 4; ++k) {
            const int i2 = l + 1 - k;
            if (i2 & 1) continue;
            const int i = i2 >> 1;
            if (i < 0 || i >= 27) continue;
            a = fmaf(y27[i], w1[co * 4 + k], a);
        }
        a = fmaf(a, sc1[co], sh1[co]);
        t1[co][l] = fmaxf(a, 0.0f);
    }
    __syncthreads();

    // conv2 (128 -> 64, 54 -> 108) + bn2 + relu. thread = 4 co x 7 l block.
    {
        const int co0 = (tid >> 4) * 4;
        const int l0  = (tid & 15) * 7;
        float acc[4][7];
        #pragma unroll
        for (int cJ = 0; cJ < 4; ++cJ) {
            const float bb = b2[co0 + cJ];
            #pragma unroll
            for (int jl = 0; jl < 7; ++jl) acc[cJ][jl] = bb;
        }
        #pragma unroll 1
        for (int ci = 0; ci < 128; ++ci) {
            float wv[4][4];
            #pragma unroll
            for (int cJ = 0; cJ < 4; ++cJ)
                #pragma unroll
                for (int k = 0; k < 4; ++k)
                    wv[cJ][k] = w2[((size_t)(ci * 64 + co0 + cJ)) * 4 + k];
            #pragma unroll
            for (int jl = 0; jl < 7; ++jl) {
                const int l = l0 + jl;
                #pragma unroll
                for (int k = 0; k < 4; ++k) {
                    const int i2 = l + 1 - k;
                    if (i2 & 1) continue;
                    const int i = i2 >> 1;
                    if (i < 0 || i >= 54) continue;
                    const float v = t1[ci][i];
                    #pragma unroll
                    for (int cJ = 0; cJ < 4; ++cJ)
                        acc[cJ][jl] = fmaf(v, wv[cJ][k], acc[cJ][jl]);
                }
            }
        }
        #pragma unroll
        for (int cJ = 0; cJ < 4; ++cJ) {
            const int co = co0 + cJ;
            const float s2  = sc2[co];
            const float h2v = sh2[co];
            #pragma unroll
            for (int jl = 0; jl < 7; ++jl) {
                const int l = l0 + jl;
                if (l < 108) t2[co][l] = fmaxf(fmaf(acc[cJ][jl], s2, h2v), 0.0f);
            }
        }
    }
    __syncthreads();

    // conv3 (64 -> 1, 108 -> 216)
    if (tid < 216) {
        const int l = tid;
        float a = b3[0];
        #pragma unroll 1
        for (int ci = 0; ci < 64; ++ci) {
            #pragma unroll
            for (int k = 0; k < 4; ++k) {
                const int i2 = l + 1 - k;
                if (i2 & 1) continue;
                const int i = i2 >> 1;
                if (i < 0 || i >= 108) continue;
                a = fmaf(t2[ci][i], w3[ci * 4 + k], a);
            }
        }
        out[(size_t)b * 216 + l] = a;
    }
}

// ---------------------------------------------------------------------------
extern "C" void kernel_launch(void* const* d_in, const int* in_sizes, int n_in,
                              void* d_out, int out_size, void* d_ws, size_t ws_size,
                              hipStream_t stream) {
    const float* x     = (const float*)d_in[0];
    const float* h0f   = (const float*)d_in[1];
    const float* c0f   = (const float*)d_in[2];
    const float* h0b   = (const float*)d_in[3];
    const float* c0b   = (const float*)d_in[4];
    const float* h0m   = (const float*)d_in[5];
    const float* c0m   = (const float*)d_in[6];
    const float* Wih_f = (const float*)d_in[7];
    const float* Whh_f = (const float*)d_in[8];
    const float* bih_f = (const float*)d_in[9];
    const float* bhh_f = (const float*)d_in[10];
    const float* Wih_b = (const float*)d_in[11];
    const float* Whh_b = (const float*)d_in[12];
    const float* bih_b = (const float*)d_in[13];
    const float* bhh_b = (const float*)d_in[14];
    const float* Wih_m = (const float*)d_in[15];
    const float* Whh_m = (const float*)d_in[16];
    const float* bih_m = (const float*)d_in[17];
    const float* bhh_m = (const float*)d_in[18];
    const float* Wd    = (const float*)d_in[19];
    const float* bd    = (const float*)d_in[20];
    const float* w1    = (const float*)d_in[21];
    const float* b1    = (const float*)d_in[22];
    const float* w2    = (const float*)d_in[23];
    const float* b2    = (const float*)d_in[24];
    const float* w3    = (const float*)d_in[25];
    const float* b3    = (const float*)d_in[26];
    const float* g1    = (const float*)d_in[27];
    const float* be1   = (const float*)d_in[28];
    const float* m1    = (const float*)d_in[29];
    const float* v1    = (const float*)d_in[30];
    const float* g2    = (const float*)d_in[31];
    const float* be2   = (const float*)d_in[32];
    const float* m2    = (const float*)d_in[33];
    const float* v2    = (const float*)d_in[34];

    const size_t HBUF = 65536000;               // one bf16 [20][100][16384]
    const size_t needA = 2 * HBUF + 13107200;   // HF + HB + HM = 144,179,200 B

    if (ws_size >= needA) {
        // ---- plan A: split kernels, high occupancy ----
        __hip_bfloat16* HF = (__hip_bfloat16*)d_ws;
        __hip_bfloat16* HB = (__hip_bfloat16*)((char*)d_ws + HBUF);
        float* HM = (float*)((char*)d_ws + 2 * HBUF);

        k_lstm100<<<dim3(256, 2), 256, 0, stream>>>(
            x, h0f, c0f, h0b, c0b,
            Wih_f, Whh_f, bih_f, bhh_f,
            Wih_b, Whh_b, bih_b, bhh_b, HF, HB, 0);

        k_mid<<<256, 512, 0, stream>>>(
            h0m, c0m, Wih_m, Whh_m, bih_m, bhh_m, HF, HB, HM);

        k_head<<<16384, 256, 0, stream>>>(
            HM, Wd, bd, w1, b1, w2, b2, w3, b3,
            g1, be1, m1, v1, g2, be2, m2, v2, (float*)d_out);
    } else {
        // ---- plan B: round-5 proven path (HB + fused fwd/mid) ----
        __hip_bfloat16* HB = (__hip_bfloat16*)d_ws;
        float* HM = (float*)((char*)d_ws + HBUF);

        k_lstm100<<<dim3(256, 1), 256, 0, stream>>>(
            x, h0f, c0f, h0b, c0b,
            Wih_f, Whh_f, bih_f, bhh_f,
            Wih_b, Whh_b, bih_b, bhh_b, HB, HB, 1);

        k_fwdmid<<<256, 256, 0, stream>>>(
            x, h0f, c0f, Wih_f, Whh_f, bih_f, bhh_f,
            h0m, c0m, Wih_m, Whh_m, bih_m, bhh_m, HB, HM);

        k_head<<<16384, 256, 0, stream>>>(
            HM, Wd, bd, w1, b1, w2, b2, w3, b3,
            g1, be1, m1, v1, g2, be2, m2, v2, (float*)d_out);
    }
}

// Round 7
// 15617.812 us; speedup vs baseline: 2.1450x; 1.2877x over previous
//
#include <hip/hip_runtime.h>
#include <hip/hip_bf16.h>

#define BTOT 16384

__device__ __forceinline__ float sig_(float x) {
    return __fdividef(1.0f, 1.0f + __expf(-x));
}
__device__ __forceinline__ float tanh_(float x) {
    float ax = fabsf(x);
    float e  = __expf(-2.0f * ax);
    float r  = __fdividef(1.0f - e, 1.0f + e);
    return x < 0.0f ? -r : r;
}

// ---------------------------------------------------------------------------
// Kernel 0: weight transpose. out[((u*K4+k4)*4+g)*4+j] = in[(g*U+u)*K + k4*4+j]
// so the 4 gates x 4 k-values for (unit u, k-chunk k4) are one 64 B block.
// ---------------------------------------------------------------------------
__global__ __launch_bounds__(256) void k_prep(
    const float* __restrict__ Win, float* __restrict__ Wout,
    int U, int K4, int n)
{
    const int e = blockIdx.x * 256 + threadIdx.x;
    if (e >= n) return;
    const int j  = e & 3;
    const int g  = (e >> 2) & 3;
    const int e4 = e >> 4;
    const int k4 = e4 % K4;
    const int u  = e4 / K4;
    const int K  = K4 * 4;
    Wout[e] = Win[(size_t)(g * U + u) * K + k4 * 4 + j];
}

// ---------------------------------------------------------------------------
// Kernel 1: the two (5 -> 100) LSTMs. grid = (256, 2), block = 512.
// 8 ragged unit-groups (4x13 + 4x12) x 64 rows -> 2 blocks/CU = 16 waves/CU.
// Whh pre-transposed: one 64 B uniform load per (unit, k4) feeds 16 FMAs.
// LDS = 35,456 B. Output H{F,B} bf16 [t][u][b].
// ---------------------------------------------------------------------------
__global__ __launch_bounds__(512, 4) void k_lstm100(
    const float* __restrict__ x,
    const float* __restrict__ h0f, const float* __restrict__ c0f,
    const float* __restrict__ h0b, const float* __restrict__ c0b,
    const float* __restrict__ WihF, const float* __restrict__ bihF,
    const float* __restrict__ bhhF,
    const float* __restrict__ WihB, const float* __restrict__ bihB,
    const float* __restrict__ bhhB,
    const float* __restrict__ WhhTF, const float* __restrict__ WhhTB,
    __hip_bfloat16* __restrict__ HF, __hip_bfloat16* __restrict__ HB)
{
    const int dir = blockIdx.y;
    const float* h0   = dir ? h0b   : h0f;
    const float* c0   = dir ? c0b   : c0f;
    const float* Wih  = dir ? WihB  : WihF;
    const float* bih  = dir ? bihB  : bihF;
    const float* bhh  = dir ? bhhB  : bhhF;
    const float* WhhT = dir ? WhhTB : WhhTF;
    __hip_bfloat16* Hout = dir ? HB : HF;

    __shared__ float h_s[64][101];
    __shared__ float wih_s[2000];    // 400 x 5
    __shared__ float bias_s[400];

    const int tid  = threadIdx.x;
    const int r    = tid & 63;
    const int ug   = __builtin_amdgcn_readfirstlane(tid >> 6);  // 0..7
    const int NU   = (ug < 4) ? 13 : 12;
    const int u0   = (ug < 4) ? ug * 13 : 52 + (ug - 4) * 12;
    const int rb   = blockIdx.x * 64;
    const int brow = rb + r;

    for (int i = tid; i < 2000; i += 512) wih_s[i] = Wih[i];
    for (int i = tid; i < 400;  i += 512) bias_s[i] = bih[i] + bhh[i];
    for (int i = tid; i < 6400; i += 512) h_s[i / 100][i % 100] = h0[(size_t)rb * 100 + i];

    float c[13];
    #pragma unroll
    for (int k = 0; k < 13; ++k)
        if (k < NU) c[k] = c0[(size_t)brow * 100 + u0 + k];
    __syncthreads();

    for (int t = 0; t < 20; ++t) {
        const int tt = dir ? (19 - t) : t;
        float xv[5];
        const float* xp = x + (size_t)tt * (BTOT * 5) + (size_t)brow * 5;
        #pragma unroll
        for (int i = 0; i < 5; ++i) xv[i] = xp[i];

        // acc = bias + Wih * x  (Wih from LDS, uniform)
        float acc[13][4];
        #pragma unroll
        for (int ju = 0; ju < 13; ++ju) {
            if (ju < NU) {
                #pragma unroll
                for (int g = 0; g < 4; ++g) {
                    const int row = g * 100 + u0 + ju;
                    float a = bias_s[row];
                    #pragma unroll
                    for (int i = 0; i < 5; ++i) a = fmaf(xv[i], wih_s[row * 5 + i], a);
                    acc[ju][g] = a;
                }
            }
        }

        // recurrent: K = 100 in chunks of 4
        #pragma unroll 1
        for (int i4 = 0; i4 < 25; ++i4) {
            const float hv0 = h_s[r][i4 * 4 + 0];
            const float hv1 = h_s[r][i4 * 4 + 1];
            const float hv2 = h_s[r][i4 * 4 + 2];
            const float hv3 = h_s[r][i4 * 4 + 3];
            #pragma unroll
            for (int ju = 0; ju < 13; ++ju) {
                if (ju < NU) {
                    const float* wp = WhhT + (((size_t)(u0 + ju) * 25 + i4) << 4);
                    #pragma unroll
                    for (int g = 0; g < 4; ++g) {
                        float a = acc[ju][g];
                        a = fmaf(hv0, wp[g * 4 + 0], a);
                        a = fmaf(hv1, wp[g * 4 + 1], a);
                        a = fmaf(hv2, wp[g * 4 + 2], a);
                        a = fmaf(hv3, wp[g * 4 + 3], a);
                        acc[ju][g] = a;
                    }
                }
            }
        }

        float hnew[13];
        #pragma unroll
        for (int ju = 0; ju < 13; ++ju) {
            if (ju < NU) {
                const float ig = sig_(acc[ju][0]);
                const float fg = sig_(acc[ju][1]);
                const float gg = tanh_(acc[ju][2]);
                const float og = sig_(acc[ju][3]);
                const float cn = fmaf(fg, c[ju], ig * gg);
                c[ju] = cn;
                hnew[ju] = og * tanh_(cn);
            }
        }
        __syncthreads();
        #pragma unroll
        for (int k = 0; k < 13; ++k) {
            if (k < NU) {
                h_s[r][u0 + k] = hnew[k];
                Hout[((size_t)tt * 100 + u0 + k) * BTOT + brow] = __float2bfloat16(hnew[k]);
            }
        }
        __syncthreads();
    }
}

// ---------------------------------------------------------------------------
// Kernel 2: middle (200 -> 200) LSTM. grid = 256, block = 1024.
// 16 ragged unit-groups (8x13 + 8x12) x 64 rows -> 16 waves/CU.
// Wih/Whh pre-transposed (64 B uniform load -> 16 FMAs). LDS = 54,912 B.
// Final h -> HM bf16 [b][u].
// ---------------------------------------------------------------------------
__global__ __launch_bounds__(1024, 4) void k_mid(
    const float* __restrict__ h0m, const float* __restrict__ c0m,
    const float* __restrict__ bih, const float* __restrict__ bhh,
    const float* __restrict__ WihT, const float* __restrict__ WhhT,
    const __hip_bfloat16* __restrict__ HF, const __hip_bfloat16* __restrict__ HB,
    __hip_bfloat16* __restrict__ HM)
{
    __shared__ float bufA[64][101];   // hf[t], then hm 0..99
    __shared__ float bufB[64][101];   // hb[t], then hm 100..199
    __shared__ float bias_s[800];

    const int tid  = threadIdx.x;
    const int r    = tid & 63;
    const int ug   = __builtin_amdgcn_readfirstlane(tid >> 6);  // 0..15
    const int NU   = (ug < 8) ? 13 : 12;
    const int u0   = (ug < 8) ? ug * 13 : 104 + (ug - 8) * 12;
    const int rb   = blockIdx.x * 64;
    const int brow = rb + r;

    for (int i = tid; i < 800; i += 1024) bias_s[i] = bih[i] + bhh[i];

    float hm[13], cm[13];
    #pragma unroll
    for (int k = 0; k < 13; ++k) {
        if (k < NU) {
            hm[k] = h0m[(size_t)brow * 200 + u0 + k];
            cm[k] = c0m[(size_t)brow * 200 + u0 + k];
        }
    }
    __syncthreads();

    for (int t = 0; t < 20; ++t) {
        // ---- S1: stage hf[t] -> bufA, hb[t] -> bufB ----
        const __hip_bfloat16* HFt = HF + (size_t)t * 100 * BTOT + rb;
        const __hip_bfloat16* HBt = HB + (size_t)t * 100 * BTOT + rb;
        for (int i = tid; i < 6400; i += 1024) {
            const int rr = i & 63;
            const int u  = i >> 6;
            bufA[rr][u] = __bfloat162float(HFt[(size_t)u * BTOT + rr]);
            bufB[rr][u] = __bfloat162float(HBt[(size_t)u * BTOT + rr]);
        }
        __syncthreads();

        // ---- S2: acc = bias + WihT * [hf|hb]  (k4 0..24 = hf, 25..49 = hb) ----
        float acc[13][4];
        #pragma unroll
        for (int ju = 0; ju < 13; ++ju)
            if (ju < NU)
                #pragma unroll
                for (int g = 0; g < 4; ++g)
                    acc[ju][g] = bias_s[g * 200 + u0 + ju];

        #pragma unroll 1
        for (int i4 = 0; i4 < 50; ++i4) {
            const float* hrow = (i4 < 25) ? &bufA[r][i4 * 4] : &bufB[r][(i4 - 25) * 4];
            const float hv0 = hrow[0];
            const float hv1 = hrow[1];
            const float hv2 = hrow[2];
            const float hv3 = hrow[3];
            #pragma unroll
            for (int ju = 0; ju < 13; ++ju) {
                if (ju < NU) {
                    const float* wp = WihT + (((size_t)(u0 + ju) * 50 + i4) << 4);
                    #pragma unroll
                    for (int g = 0; g < 4; ++g) {
                        float a = acc[ju][g];
                        a = fmaf(hv0, wp[g * 4 + 0], a);
                        a = fmaf(hv1, wp[g * 4 + 1], a);
                        a = fmaf(hv2, wp[g * 4 + 2], a);
                        a = fmaf(hv3, wp[g * 4 + 3], a);
                        acc[ju][g] = a;
                    }
                }
            }
        }
        __syncthreads();          // done reading hf/hb tiles

        // ---- S3: publish hm[t-1]: units 0..99 -> bufA, 100..199 -> bufB ----
        #pragma unroll
        for (int k = 0; k < 13; ++k) {
            if (k < NU) {
                const int u = u0 + k;
                if (u < 100) bufA[r][u] = hm[k];
                else         bufB[r][u - 100] = hm[k];
            }
        }
        __syncthreads();

        // ---- S4: acc += WhhT * hm; gates ----
        #pragma unroll 1
        for (int i4 = 0; i4 < 50; ++i4) {
            const float* hrow = (i4 < 25) ? &bufA[r][i4 * 4] : &bufB[r][(i4 - 25) * 4];
            const float hv0 = hrow[0];
            const float hv1 = hrow[1];
            const float hv2 = hrow[2];
            const float hv3 = hrow[3];
            #pragma unroll
            for (int ju = 0; ju < 13; ++ju) {
                if (ju < NU) {
                    const float* wp = WhhT + (((size_t)(u0 + ju) * 50 + i4) << 4);
                    #pragma unroll
                    for (int g = 0; g < 4; ++g) {
                        float a = acc[ju][g];
                        a = fmaf(hv0, wp[g * 4 + 0], a);
                        a = fmaf(hv1, wp[g * 4 + 1], a);
                        a = fmaf(hv2, wp[g * 4 + 2], a);
                        a = fmaf(hv3, wp[g * 4 + 3], a);
                        acc[ju][g] = a;
                    }
                }
            }
        }
        #pragma unroll
        for (int ju = 0; ju < 13; ++ju) {
            if (ju < NU) {
                const float ig = sig_(acc[ju][0]);
                const float fg = sig_(acc[ju][1]);
                const float gg = tanh_(acc[ju][2]);
                const float og = sig_(acc[ju][3]);
                const float cn = fmaf(fg, cm[ju], ig * gg);
                cm[ju] = cn;
                hm[ju] = og * tanh_(cn);
            }
        }
        __syncthreads();          // protect bufA/bufB before next S1
    }

    #pragma unroll
    for (int k = 0; k < 13; ++k)
        if (k < NU)
            HM[(size_t)brow * 200 + u0 + k] = __float2bfloat16(hm[k]);
}

// ---------------------------------------------------------------------------
// Kernel 3: dense (200->27) + convT1+bn+relu + convT2+bn+relu + convT3.
// grid = 16384, block = 256. HM input bf16, f32 output. LDS = 57,740 B.
// ---------------------------------------------------------------------------
__global__ __launch_bounds__(256) void k_head(
    const __hip_bfloat16* __restrict__ HM,
    const float* __restrict__ Wd, const float* __restrict__ bd,
    const float* __restrict__ w1, const float* __restrict__ b1,
    const float* __restrict__ w2, const float* __restrict__ b2,
    const float* __restrict__ w3, const float* __restrict__ b3,
    const float* __restrict__ g1, const float* __restrict__ be1,
    const float* __restrict__ m1, const float* __restrict__ v1,
    const float* __restrict__ g2, const float* __restrict__ be2,
    const float* __restrict__ m2, const float* __restrict__ v2,
    float* __restrict__ out)
{
    __shared__ float hm_s[200];
    __shared__ float y27[27];
    __shared__ float t1[128][54];
    __shared__ float t2[64][108];
    __shared__ float sc1[128], sh1[128], sc2[64], sh2[64];

    const int tid = threadIdx.x;
    const int b   = blockIdx.x;

    if (tid < 200) hm_s[tid] = __bfloat162float(HM[(size_t)b * 200 + tid]);
    if (tid < 128) {
        const float s = g1[tid] * __frsqrt_rn(v1[tid] + 1e-5f);
        sc1[tid] = s; sh1[tid] = be1[tid] - m1[tid] * s;
    } else if (tid < 192) {
        const int cc = tid - 128;
        const float s = g2[cc] * __frsqrt_rn(v2[cc] + 1e-5f);
        sc2[cc] = s; sh2[cc] = be2[cc] - m2[cc] * s;
    }
    __syncthreads();

    if (tid < 27) {                                   // dense 200 -> 27
        float a = bd[tid];
        const float* wr = Wd + tid * 200;
        for (int i = 0; i < 200; ++i) a = fmaf(hm_s[i], wr[i], a);
        y27[tid] = a;
    }
    __syncthreads();

    // conv1 (1 -> 128, 27 -> 54) + bn1 + relu
    for (int idx = tid; idx < 128 * 54; idx += 256) {
        const int co = idx / 54;
        const int l  = idx - co * 54;
        float a = b1[co];
        #pragma unroll
        for (int k = 0; k < 4; ++k) {
            const int i2 = l + 1 - k;
            if (i2 & 1) continue;
            const int i = i2 >> 1;
            if (i < 0 || i >= 27) continue;
            a = fmaf(y27[i], w1[co * 4 + k], a);
        }
        a = fmaf(a, sc1[co], sh1[co]);
        t1[co][l] = fmaxf(a, 0.0f);
    }
    __syncthreads();

    // conv2 (128 -> 64, 54 -> 108) + bn2 + relu. thread = 4 co x 7 l block.
    {
        const int co0 = (tid >> 4) * 4;
        const int l0  = (tid & 15) * 7;
        float acc[4][7];
        #pragma unroll
        for (int cJ = 0; cJ < 4; ++cJ) {
            const float bb = b2[co0 + cJ];
            #pragma unroll
            for (int jl = 0; jl < 7; ++jl) acc[cJ][jl] = bb;
        }
        #pragma unroll 1
        for (int ci = 0; ci < 128; ++ci) {
            float wv[4][4];
            #pragma unroll
            for (int cJ = 0; cJ < 4; ++cJ)
                #pragma unroll
                for (int k = 0; k < 4; ++k)
                    wv[cJ][k] = w2[((size_t)(ci * 64 + co0 + cJ)) * 4 + k];
            #pragma unroll
            for (int jl = 0; jl < 7; ++jl) {
                const int l = l0 + jl;
                #pragma unroll
                for (int k = 0; k < 4; ++k) {
                    const int i2 = l + 1 - k;
                    if (i2 & 1) continue;
                    const int i = i2 >> 1;
                    if (i < 0 || i >= 54) continue;
                    const float v = t1[ci][i];
                    #pragma unroll
                    for (int cJ = 0; cJ < 4; ++cJ)
                        acc[cJ][jl] = fmaf(v, wv[cJ][k], acc[cJ][jl]);
                }
            }
        }
        #pragma unroll
        for (int cJ = 0; cJ < 4; ++cJ) {
            const int co = co0 + cJ;
            const float s2  = sc2[co];
            const float h2v = sh2[co];
            #pragma unroll
            for (int jl = 0; jl < 7; ++jl) {
                const int l = l0 + jl;
                if (l < 108) t2[co][l] = fmaxf(fmaf(acc[cJ][jl], s2, h2v), 0.0f);
            }
        }
    }
    __syncthreads();

    // conv3 (64 -> 1, 108 -> 216)
    if (tid < 216) {
        const int l = tid;
        float a = b3[0];
        #pragma unroll 1
        for (int ci = 0; ci < 64; ++ci) {
            #pragma unroll
            for (int k = 0; k < 4; ++k) {
                const int i2 = l + 1 - k;
                if (i2 & 1) continue;
                const int i = i2 >> 1;
                if (i < 0 || i >= 108) continue;
                a = fmaf(t2[ci][i], w3[ci * 4 + k], a);
            }
        }
        out[(size_t)b * 216 + l] = a;
    }
}

// ---------------------------------------------------------------------------
extern "C" void kernel_launch(void* const* d_in, const int* in_sizes, int n_in,
                              void* d_out, int out_size, void* d_ws, size_t ws_size,
                              hipStream_t stream) {
    const float* x     = (const float*)d_in[0];
    const float* h0f   = (const float*)d_in[1];
    const float* c0f   = (const float*)d_in[2];
    const float* h0b   = (const float*)d_in[3];
    const float* c0b   = (const float*)d_in[4];
    const float* h0m   = (const float*)d_in[5];
    const float* c0m   = (const float*)d_in[6];
    const float* Wih_f = (const float*)d_in[7];
    const float* Whh_f = (const float*)d_in[8];
    const float* bih_f = (const float*)d_in[9];
    const float* bhh_f = (const float*)d_in[10];
    const float* Wih_b = (const float*)d_in[11];
    const float* Whh_b = (const float*)d_in[12];
    const float* bih_b = (const float*)d_in[13];
    const float* bhh_b = (const float*)d_in[14];
    const float* Wih_m = (const float*)d_in[15];
    const float* Whh_m = (const float*)d_in[16];
    const float* bih_m = (const float*)d_in[17];
    const float* bhh_m = (const float*)d_in[18];
    const float* Wd    = (const float*)d_in[19];
    const float* bd    = (const float*)d_in[20];
    const float* w1    = (const float*)d_in[21];
    const float* b1    = (const float*)d_in[22];
    const float* w2    = (const float*)d_in[23];
    const float* b2    = (const float*)d_in[24];
    const float* w3    = (const float*)d_in[25];
    const float* b3    = (const float*)d_in[26];
    const float* g1    = (const float*)d_in[27];
    const float* be1   = (const float*)d_in[28];
    const float* m1    = (const float*)d_in[29];
    const float* v1    = (const float*)d_in[30];
    const float* g2    = (const float*)d_in[31];
    const float* be2   = (const float*)d_in[32];
    const float* m2    = (const float*)d_in[33];
    const float* v2    = (const float*)d_in[34];

    // ws layout (bytes), total 139,225,600 <= proven 144,179,200:
    //   HF bf16 [20][100][16384]      @ 0           (65,536,000)
    //   HB bf16 [20][100][16384]      @ 65,536,000  (65,536,000)
    //   WihT_m f32 [200][50][4][4]    @ 131,072,000 (640,000)
    //   WhhT_m f32 [200][50][4][4]    @ 131,712,000 (640,000)
    //   WhhT_f f32 [100][25][4][4]    @ 132,352,000 (160,000)
    //   WhhT_b f32 [100][25][4][4]    @ 132,512,000 (160,000)
    //   HM  bf16 [16384][200]         @ 132,672,000 (6,553,600)
    char* ws = (char*)d_ws;
    __hip_bfloat16* HF = (__hip_bfloat16*)ws;
    __hip_bfloat16* HB = (__hip_bfloat16*)(ws + 65536000);
    float* WihT_m = (float*)(ws + 131072000);
    float* WhhT_m = (float*)(ws + 131712000);
    float* WhhT_f = (float*)(ws + 132352000);
    float* WhhT_b = (float*)(ws + 132512000);
    __hip_bfloat16* HM = (__hip_bfloat16*)(ws + 132672000);

    k_prep<<<(160000 + 255) / 256, 256, 0, stream>>>(Wih_m, WihT_m, 200, 50, 160000);
    k_prep<<<(160000 + 255) / 256, 256, 0, stream>>>(Whh_m, WhhT_m, 200, 50, 160000);
    k_prep<<<(40000  + 255) / 256, 256, 0, stream>>>(Whh_f, WhhT_f, 100, 25, 40000);
    k_prep<<<(40000  + 255) / 256, 256, 0, stream>>>(Whh_b, WhhT_b, 100, 25, 40000);

    k_lstm100<<<dim3(256, 2), 512, 0, stream>>>(
        x, h0f, c0f, h0b, c0b,
        Wih_f, bih_f, bhh_f,
        Wih_b, bih_b, bhh_b,
        WhhT_f, WhhT_b, HF, HB);

    k_mid<<<256, 1024, 0, stream>>>(
        h0m, c0m, bih_m, bhh_m, WihT_m, WhhT_m, HF, HB, HM);

    k_head<<<16384, 256, 0, stream>>>(
        HM, Wd, bd, w1, b1, w2, b2, w3, b3,
        g1, be1, m1, v1, g2, be2, m2, v2, (float*)d_out);
}